// Round 1
// baseline (146.094 us; speedup 1.0000x reference)
//
#include <hip/hip_runtime.h>
#include <hip/hip_bf16.h>

// HeteroLinear: out[b,n,o] = sum_i x[b,n,i] * W[t[n]][o][i] + bias[t[n]][o]
// B=16, N=16384, F_IN=F_OUT=128, NUM_TYPES=16, fp32 in/out.
//
// Strategy: one wave per node n. Output tile is 16(B) x 128(F_OUT):
// 8 o-tiles of mfma_f32_16x16x32_bf16, K-loop of 4 steps over F_IN=128.
// fp32 accuracy via hi/lo bf16 split of x (2 MFMAs into same f32 acc).
// W read as f32 from global (L2-resident, 1 MB) and converted inline.

#define NN 16384
#define FF 128

typedef __bf16 bf16x8 __attribute__((ext_vector_type(8)));
typedef float  f32x4  __attribute__((ext_vector_type(4)));

__global__ __launch_bounds__(256) void HeteroLinear_kernel(
    const float* __restrict__ x,      // [16][NN][128]
    const int*   __restrict__ tv,     // [NN]
    const float* __restrict__ W,      // [16][128][128]  (W[t][o][i])
    const float* __restrict__ bias,   // [16][128]
    float*       __restrict__ out)    // [16][NN][128]
{
    const int lane = threadIdx.x & 63;
    const int wave = threadIdx.x >> 6;
    const int n    = blockIdx.x * 4 + wave;

    const int lrow = lane & 15;   // A row (b) / B col (o) / D col (o)
    const int lgrp = lane >> 4;   // 0..3: k-group of 8 for A/B, row-group for D

    const int t = tv[n];
    const float* Wt = W + (size_t)t * (FF * FF);

    f32x4 acc[8];
#pragma unroll
    for (int i = 0; i < 8; ++i) acc[i] = (f32x4){0.f, 0.f, 0.f, 0.f};

    // lane's slice of x: row b=lrow, k base = lgrp*8
    const float* xrow = x + (size_t)lrow * ((size_t)NN * FF) + (size_t)n * FF + lgrp * 8;

#pragma unroll
    for (int kk = 0; kk < 4; ++kk) {
        const float* xp = xrow + kk * 32;
        f32x4 v0 = *(const f32x4*)(xp);
        f32x4 v1 = *(const f32x4*)(xp + 4);

        bf16x8 ahi, alo;
#pragma unroll
        for (int j = 0; j < 4; ++j) {
            __bf16 h0 = (__bf16)v0[j];
            ahi[j]     = h0;
            alo[j]     = (__bf16)(v0[j] - (float)h0);
            __bf16 h1 = (__bf16)v1[j];
            ahi[4 + j] = h1;
            alo[4 + j] = (__bf16)(v1[j] - (float)h1);
        }

#pragma unroll
        for (int ot = 0; ot < 8; ++ot) {
            // B-frag: B[k][o] = W[t][o][k]; lane holds o=ot*16+lrow, k=kk*32+lgrp*8..+7
            const float* wp = Wt + (size_t)(ot * 16 + lrow) * FF + kk * 32 + lgrp * 8;
            f32x4 w0 = *(const f32x4*)(wp);
            f32x4 w1 = *(const f32x4*)(wp + 4);
            bf16x8 bf;
#pragma unroll
            for (int j = 0; j < 4; ++j) {
                bf[j]     = (__bf16)w0[j];
                bf[4 + j] = (__bf16)w1[j];
            }
            acc[ot] = __builtin_amdgcn_mfma_f32_16x16x32_bf16(ahi, bf, acc[ot], 0, 0, 0);
            acc[ot] = __builtin_amdgcn_mfma_f32_16x16x32_bf16(alo, bf, acc[ot], 0, 0, 0);
        }
    }

    // Epilogue: D col = o = ot*16 + lrow; D row (b) = lgrp*4 + r
#pragma unroll
    for (int ot = 0; ot < 8; ++ot) {
        const int o = ot * 16 + lrow;
        const float bv = bias[t * FF + o];
#pragma unroll
        for (int r = 0; r < 4; ++r) {
            const int row = lgrp * 4 + r;
            out[(size_t)row * ((size_t)NN * FF) + (size_t)n * FF + o] = acc[ot][r] + bv;
        }
    }
}

extern "C" void kernel_launch(void* const* d_in, const int* in_sizes, int n_in,
                              void* d_out, int out_size, void* d_ws, size_t ws_size,
                              hipStream_t stream) {
    const float* x    = (const float*)d_in[0];
    const int*   tv   = (const int*)d_in[1];
    const float* W    = (const float*)d_in[2];
    const float* bias = (const float*)d_in[3];
    float*       out  = (float*)d_out;

    const int N = in_sizes[1];          // 16384 nodes
    dim3 grid(N / 4), block(256);       // 4 waves/block, 1 node/wave
    hipLaunchKernelGGL(HeteroLinear_kernel, grid, block, 0, stream,
                       x, tv, W, bias, out);
}